// Round 11
// baseline (58.902 us; speedup 1.0000x reference)
//
#include <hip/hip_runtime.h>
#include <stdint.h>

#define IMW 512
#define HW 262144  // 512*512

typedef unsigned long long ull;
typedef __attribute__((ext_vector_type(4))) float f32x4;
typedef __attribute__((ext_vector_type(8))) _Float16 h8;

// ---------------------------------------------------------------------------
// k1: LIF scan over 64 frames, 1 column per thread (2048 blocks). Best-
// measured structure (45 µs, 2.84 TB/s delivered read = ~90% of the chip's
// demonstrated streaming-read rate; scalar/float4/NT/occupancy variants all
// land 2.6-2.9 TB/s -> read-path ceiling, 128 MB input irreducible).
// v = fmaf(x - v, 0.1f, v) (== v + (x-v)/10 up to ~1e-6; spike margin
// >=1.2e-3 for inputs in [0,1)). Depth-8 double-buffered prefetch.
// Output: per-column spike history R2[enc][y][x], coalesced stores.
// ---------------------------------------------------------------------------
__global__ __launch_bounds__(256) void k1_lif(
    const float* __restrict__ on, const float* __restrict__ off,
    ull* __restrict__ R2) {
  int enc = blockIdx.z;
  const float* ev = enc ? off : on;
  int row = blockIdx.y;
  int x = blockIdx.x * 256 + threadIdx.x;
  const float* p = ev + (size_t)row * IMW + x;
  float v = 0.0f;
  unsigned hlo = 0, hhi = 0;
  float buf[16];
#pragma unroll
  for (int j = 0; j < 8; ++j) buf[j] = p[(size_t)j * HW];
#pragma unroll
  for (int batch = 0; batch < 8; ++batch) {
    if (batch < 7) {
#pragma unroll
      for (int j = 0; j < 8; ++j)
        buf[(((batch + 1) & 1) << 3) + j] = p[(size_t)((batch + 1) * 8 + j) * HW];
    }
#pragma unroll
    for (int j = 0; j < 8; ++j) {
      int t = batch * 8 + j;
      float xv = buf[((batch & 1) << 3) + j];
      v = fmaf(xv - v, 0.1f, v);
      bool s = (v >= 1.0f);
      if (s) v = 0.0f;
      if (t < 32) hlo |= s ? (1u << t) : 0u;
      else        hhi |= s ? (1u << (t - 32)) : 0u;
    }
  }
  R2[((size_t)enc * IMW + row) * IMW + x] = ((ull)hhi << 32) | hlo;
}

// ---------------------------------------------------------------------------
// k2: encoder convs. Tile 64x4 output pixels, 1 px/thread. Reads per-column
// histories; fast path: if no spike in the tile's 8x68 halo, output is 0.
// Slow path (correct for arbitrary inputs): ballot-transpose histories into
// per-t row bitmaps, then table-based conv1 + register conv2.
// ---------------------------------------------------------------------------
__global__ __launch_bounds__(256) void k2_enc(
    const ull* __restrict__ R2, const float* __restrict__ on_w1,
    const float* __restrict__ on_w2, const float* __restrict__ off_w1,
    const float* __restrict__ off_w2, float* __restrict__ means) {
  __shared__ ull hist[8][68];     // [local row r0-2..r0+5][col wcb*64-2..+65]
  __shared__ ull spk[64][8][2];   // [t][local row][A,B]
  __shared__ float4 t1v[512];     // relu(conv1) per 9-bit pattern
  int tid = threadIdx.x;
  int enc = blockIdx.z;
  int wcb = blockIdx.x;           // 64-column word index 0..7
  int r0 = blockIdx.y * 4;
  ull any = 0;
#pragma unroll
  for (int rep = 0; rep < 3; ++rep) {
    int idx = tid + 256 * rep;
    if (idx < 544) {
      int row = idx / 68, col = idx % 68;
      int gy = r0 - 2 + row, gx = wcb * 64 - 2 + col;
      ull h = 0;
      if (gy >= 0 && gy < IMW && gx >= 0 && gx < IMW)
        h = R2[((size_t)enc * IMW + gy) * IMW + gx];
      hist[row][col] = h;
      any |= h;
    }
  }
  int lane = tid & 63, wv = tid >> 6;
  int c = wcb * 64 + lane;
  int r = r0 + wv;
  float* outp = means + (size_t)enc * HW + r * IMW + c;
  int nz = __syncthreads_or(any != 0ull);
  if (!nz) { *outp = 0.0f; return; }

  // ---- slow path (not executed for all-zero spikes, but fully correct) ----
  // transpose hist -> spk: wave wv handles rows 2wv, 2wv+1
#pragma unroll 1
  for (int r2 = 0; r2 < 2; ++r2) {
    int row = wv * 2 + r2;
    ull hA = hist[row][lane];       // bit i of word A = col C-2+i
    ull hB = hist[row][lane + 4];   // bit i of word B = col C+2+i
    for (int t = 0; t < 64; ++t) {
      ull wA = __ballot((unsigned)((hA >> t) & 1ull));
      ull wB = __ballot((unsigned)((hB >> t) & 1ull));
      if (lane == t) { spk[t][row][0] = wA; spk[t][row][1] = wB; }
    }
  }
  const float* w1 = enc ? off_w1 : on_w1;
  const float* w2 = enc ? off_w2 : on_w2;
#pragma unroll
  for (int i = 0; i < 2; ++i) {
    int e = tid + 256 * i;
    float a0 = 0.f, a1 = 0.f, a2 = 0.f, a3 = 0.f;
#pragma unroll
    for (int k = 0; k < 9; ++k) {
      if (e & (1 << k)) {
        a0 += w1[k]; a1 += w1[9 + k]; a2 += w1[18 + k]; a3 += w1[27 + k];
      }
    }
    t1v[e] = make_float4(fmaxf(a0, 0.f), fmaxf(a1, 0.f),
                         fmaxf(a2, 0.f), fmaxf(a3, 0.f));
  }
  __syncthreads();
  float w2g[36];
#pragma unroll
  for (int i = 0; i < 36; ++i) w2g[i] = w2[i];
  float fm[9];   // conv2 zero-padding masks
#pragma unroll
  for (int qi = 0; qi < 3; ++qi)
#pragma unroll
    for (int dx = 0; dx < 3; ++dx) {
      int q = r - 1 + qi, xp = c - 1 + dx;
      fm[qi * 3 + dx] =
          (q >= 0 && q < IMW && xp >= 0 && xp < IMW) ? 1.0f : 0.0f;
    }
  int selB = (lane >= 60) ? 1 : 0;
  int shamt = selB ? lane - 4 : lane;
  float acc = 0.0f;
  for (int t = 0; t < 64; ++t) {
    unsigned r5[5];
#pragma unroll
    for (int k = 0; k < 5; ++k)
      r5[k] = (unsigned)((spk[t][wv + k][selB] >> shamt) & 31ull);
    float sum = 0.0f;
#pragma unroll
    for (int qi = 0; qi < 3; ++qi) {
#pragma unroll
      for (int dx = 0; dx < 3; ++dx) {
        unsigned pat = ((r5[qi] >> dx) & 7u) |
                       (((r5[qi + 1] >> dx) & 7u) << 3) |
                       (((r5[qi + 2] >> dx) & 7u) << 6);
        float4 sv = t1v[pat];
        int j = qi * 3 + dx;
        float d = w2g[j] * sv.x + w2g[9 + j] * sv.y + w2g[18 + j] * sv.z +
                  w2g[27 + j] * sv.w;
        sum = fmaf(fm[j], d, sum);
      }
    }
    acc += fmaxf(sum, 0.0f);
  }
  *outp = acc * (1.0f / 64.0f);
}

// ---------------------------------------------------------------------------
// k3: clip convs, fused, now including weight prep (old k0) in the prologue:
// each block redundantly builds w1s (f32, [tap*16+oc]) and w2s (f16,
// [oc*160+k], k=tap*16+ic, zero-padded to K=160) in LDS from the raw
// clip weights -- removes the separate k0 dispatch.
// Phase1 (VALU fp32): stage = relu(conv1+b1) for tile+halo (10x66 positions),
//   zeroed outside the image (= conv2 zero padding), stored as f16 [pos][16ch].
// Phase2 (MFMA f16): conv2 as GEMM M=512 px, N=32 oc, K=144 (tap-major,
//   padded to 160). A-frag = ONE ds_read_b128 (8 lanes/bank-group, no
//   conflicts). B-frags held in VGPRs. D: oc=lane&15, px=(l>>4)*4+reg.
// Output stored non-temporally (write-once, never re-read in-pipeline).
// ---------------------------------------------------------------------------
__global__ __launch_bounds__(256) void k3_clip(
    const float* __restrict__ means, const float* __restrict__ rgb,
    const float* __restrict__ cw1, const float* __restrict__ b1,
    const float* __restrict__ cw2, const float* __restrict__ b2,
    float* __restrict__ out) {
  __shared__ __align__(16) float xs[5][12][68];        // input tile + halo
  __shared__ __align__(16) _Float16 stage[660 * 16];   // [pos][ic] f16
  __shared__ __align__(16) float w1s[720];             // conv1 weights
  __shared__ __align__(16) _Float16 w2s[5120];         // conv2 weights, padded
  int tid = threadIdx.x;
  int c0 = blockIdx.x * 64;
  int r0 = blockIdx.y * 8;
  // ---- weight prep (old k0), redundant per block, L2-served
#pragma unroll
  for (int rep = 0; rep < 20; ++rep) {
    int i = tid + 256 * rep;
    if (i < 5120) {
      int oc = i / 160, k = i % 160;
      int tap = k >> 4, ic = k & 15;
      w2s[i] = (tap < 9) ? (_Float16)cw2[oc * 144 + ic * 9 + tap]
                         : (_Float16)0.0f;
    }
    if (i < 720) {
      int oc = i / 45, tap = i % 45;
      w1s[tap * 16 + oc] = cw1[i];
    }
  }
  // ---- load x tile (On mean, Off mean, rgb x3), zero-padded: 4080 elems
#pragma unroll
  for (int k = 0; k < 16; ++k) {
    int idx = tid + 256 * k;
    if (idx < 4080) {
      int ch = idx / 816, rem = idx % 816;
      int row = rem / 68, col = rem % 68;
      int gy = r0 - 2 + row, gx = c0 - 2 + col;
      float val = 0.0f;
      if (gy >= 0 && gy < IMW && gx >= 0 && gx < IMW) {
        val = (ch < 2) ? means[(size_t)ch * HW + gy * IMW + gx]
                       : rgb[(size_t)(ch - 2) * HW + gy * IMW + gx];
      }
      xs[ch][row][col] = val;
    }
  }
  __syncthreads();
  // ---- phase 1: conv1 at 660 stage positions (10 x 66), <=3 per thread
#pragma unroll 1
  for (int rep = 0; rep < 3; ++rep) {
    int p = tid + (rep << 8);
    if (p < 660) {
      int sr = p / 66, sc = p % 66;
      float a[16];
#pragma unroll
      for (int oc = 0; oc < 16; ++oc) a[oc] = b1[oc];
#pragma unroll 1
      for (int ic = 0; ic < 5; ++ic) {
        const float* xp = &xs[ic][sr][sc];
#pragma unroll
        for (int dy = 0; dy < 3; ++dy) {
#pragma unroll
          for (int dx = 0; dx < 3; ++dx) {
            float x = xp[dy * 68 + dx];
            const float* wrow = &w1s[(ic * 9 + dy * 3 + dx) * 16];
#pragma unroll
            for (int oc = 0; oc < 16; ++oc)
              a[oc] = fmaf(wrow[oc], x, a[oc]);
          }
        }
      }
      int q = r0 - 1 + sr, gxp = c0 - 1 + sc;
      float msk =
          (q >= 0 && q < IMW && gxp >= 0 && gxp < IMW) ? 1.0f : 0.0f;
      unsigned w[8];
#pragma unroll
      for (int j = 0; j < 8; ++j) {
        unsigned lo = (unsigned)__builtin_bit_cast(
            unsigned short, (_Float16)(msk * fmaxf(a[2 * j], 0.f)));
        unsigned hi = (unsigned)__builtin_bit_cast(
            unsigned short, (_Float16)(msk * fmaxf(a[2 * j + 1], 0.f)));
        w[j] = lo | (hi << 16);
      }
      uint4* dst = (uint4*)((char*)stage + p * 32);
      dst[0] = make_uint4(w[0], w[1], w[2], w[3]);
      dst[1] = make_uint4(w[4], w[5], w[6], w[7]);
    }
  }
  __syncthreads();
  // ---- phase 2: conv2 via MFMA. Wave og owns m-tiles og*8 .. og*8+7.
  int og = __builtin_amdgcn_readfirstlane(tid >> 6);
  int lane = tid & 63;
  int xl = lane & 15;
  int quad = lane >> 4;          // 0..3
  int ichalf = quad & 1;
  int q2 = quad >> 1;            // tap parity within chunk
  int myoff[5];
#pragma unroll
  for (int c = 0; c < 5; ++c) {
    int tap = 2 * c + q2;
    if (tap > 8) tap = 8;
    myoff[c] = ((tap / 3) * 66 + (tap % 3)) * 32;
  }
  h8 bf[5][2];
  const char* wb = (const char*)w2s;
#pragma unroll
  for (int c = 0; c < 5; ++c) {
#pragma unroll
    for (int nt = 0; nt < 2; ++nt) {
      int oc = nt * 16 + xl;
      f32x4 t = *(const f32x4*)(wb + oc * 320 + c * 64 + quad * 16);
      bf[c][nt] = __builtin_bit_cast(h8, t);
    }
  }
  float bias0 = b2[xl];
  float bias1 = b2[16 + xl];
#pragma unroll 1
  for (int mi = 0; mi < 8; ++mi) {
    int m = og * 8 + mi;
    int py = m >> 2;
    int x0 = (m & 3) << 4;
    int bb = ((py * 66 + x0 + xl) << 5) + (ichalf << 4);
    f32x4 acc0 = {0.f, 0.f, 0.f, 0.f};
    f32x4 acc1 = {0.f, 0.f, 0.f, 0.f};
#pragma unroll
    for (int c = 0; c < 5; ++c) {
      f32x4 ar = *(const f32x4*)((const char*)stage + bb + myoff[c]);
      h8 af = __builtin_bit_cast(h8, ar);
      acc0 = __builtin_amdgcn_mfma_f32_16x16x32_f16(af, bf[c][0], acc0, 0, 0, 0);
      acc1 = __builtin_amdgcn_mfma_f32_16x16x32_f16(af, bf[c][1], acc1, 0, 0, 0);
    }
    int px = c0 + x0 + ((lane >> 4) << 2);
    float* o0 = out + (size_t)xl * HW + (r0 + py) * IMW + px;
    float* o1 = o0 + (size_t)16 * HW;
    f32x4 r0v = {fmaxf(acc0[0] + bias0, 0.f), fmaxf(acc0[1] + bias0, 0.f),
                 fmaxf(acc0[2] + bias0, 0.f), fmaxf(acc0[3] + bias0, 0.f)};
    f32x4 r1v = {fmaxf(acc1[0] + bias1, 0.f), fmaxf(acc1[1] + bias1, 0.f),
                 fmaxf(acc1[2] + bias1, 0.f), fmaxf(acc1[3] + bias1, 0.f)};
    __builtin_nontemporal_store(r0v, (f32x4*)o0);
    __builtin_nontemporal_store(r1v, (f32x4*)o1);
  }
}

// ---------------------------------------------------------------------------
extern "C" void kernel_launch(void* const* d_in, const int* in_sizes, int n_in,
                              void* d_out, int out_size, void* d_ws,
                              size_t ws_size, hipStream_t stream) {
  const float* on_ev  = (const float*)d_in[0];
  const float* off_ev = (const float*)d_in[1];
  const float* rgb    = (const float*)d_in[2];
  const float* on_w1  = (const float*)d_in[3];
  const float* on_w2  = (const float*)d_in[4];
  const float* off_w1 = (const float*)d_in[5];
  const float* off_w2 = (const float*)d_in[6];
  const float* cw1    = (const float*)d_in[7];
  const float* cb1    = (const float*)d_in[8];
  const float* cw2    = (const float*)d_in[9];
  const float* cb2    = (const float*)d_in[10];
  float* out = (float*)d_out;
  char* ws = (char*)d_ws;
  ull* R2 = (ull*)ws;                         // 4 MB: per-column histories
  float* means = (float*)(ws + (4u << 20));   // 2 MB: On/Off mean maps

  hipLaunchKernelGGL(k1_lif, dim3(2, 512, 2), dim3(256), 0, stream,
                     on_ev, off_ev, R2);
  hipLaunchKernelGGL(k2_enc, dim3(8, 128, 2), dim3(256), 0, stream,
                     R2, on_w1, on_w2, off_w1, off_w2, means);
  hipLaunchKernelGGL(k3_clip, dim3(8, 64), dim3(256), 0, stream,
                     means, rgb, cw1, cb1, cw2, cb2, out);
}

// Round 12
// 55.531 us; speedup vs baseline: 1.0607x; 1.0607x over previous
//
#include <hip/hip_runtime.h>
#include <stdint.h>

#define IMW 512
#define HW 262144  // 512*512

typedef unsigned long long ull;
typedef __attribute__((ext_vector_type(4))) float f32x4;
typedef __attribute__((ext_vector_type(8))) _Float16 h8;

// ---------------------------------------------------------------------------
// k0: weight prep.
// w1r[tap*16 + oc] = clip_w1[oc][tap]  (f32, tap = ic*9 + dy*3+dx), for conv1.
// w2h[oc*160 + k]  = clip_w2[oc][ic][j] as f16, k = tap*16+ic (j=tap=dy*3+dx),
//                    zero for k >= 144 (K padded to 5 chunks of 32).
// Kept as a separate tiny dispatch: fusing it per-k3-block (R11) cost ~3 us
// of redundant uncoalesced reads vs ~1.5 us of launch overhead.
// ---------------------------------------------------------------------------
__global__ __launch_bounds__(256) void k0_rearrange(
    const float* __restrict__ cw2, const float* __restrict__ cw1,
    _Float16* __restrict__ w2h, float* __restrict__ w1r) {
  int i = blockIdx.x * 256 + threadIdx.x;
  if (i < 5120) {
    int oc = i / 160, k = i % 160;
    int tap = k >> 4, ic = k & 15;
    float v = (tap < 9) ? cw2[oc * 144 + ic * 9 + tap] : 0.0f;
    w2h[i] = (_Float16)v;
  }
  if (i < 720) {
    int oc = i / 45, tap = i % 45;
    w1r[tap * 16 + oc] = cw1[i];
  }
}

// ---------------------------------------------------------------------------
// k1: LIF scan over 64 frames, 1 column per thread (2048 blocks). Best-
// measured structure (45 µs, 2.84 TB/s delivered read = ~90% of the chip's
// demonstrated streaming-read rate; scalar/float4/NT/occupancy variants all
// land 2.6-2.9 TB/s -> read-path ceiling, 128 MB input irreducible).
// v = fmaf(x - v, 0.1f, v) (== v + (x-v)/10 up to ~1e-6; spike margin
// >=1.2e-3 for inputs in [0,1)). Depth-8 double-buffered prefetch.
// Output: per-column spike history R2[enc][y][x], coalesced stores.
// ---------------------------------------------------------------------------
__global__ __launch_bounds__(256) void k1_lif(
    const float* __restrict__ on, const float* __restrict__ off,
    ull* __restrict__ R2) {
  int enc = blockIdx.z;
  const float* ev = enc ? off : on;
  int row = blockIdx.y;
  int x = blockIdx.x * 256 + threadIdx.x;
  const float* p = ev + (size_t)row * IMW + x;
  float v = 0.0f;
  unsigned hlo = 0, hhi = 0;
  float buf[16];
#pragma unroll
  for (int j = 0; j < 8; ++j) buf[j] = p[(size_t)j * HW];
#pragma unroll
  for (int batch = 0; batch < 8; ++batch) {
    if (batch < 7) {
#pragma unroll
      for (int j = 0; j < 8; ++j)
        buf[(((batch + 1) & 1) << 3) + j] = p[(size_t)((batch + 1) * 8 + j) * HW];
    }
#pragma unroll
    for (int j = 0; j < 8; ++j) {
      int t = batch * 8 + j;
      float xv = buf[((batch & 1) << 3) + j];
      v = fmaf(xv - v, 0.1f, v);
      bool s = (v >= 1.0f);
      if (s) v = 0.0f;
      if (t < 32) hlo |= s ? (1u << t) : 0u;
      else        hhi |= s ? (1u << (t - 32)) : 0u;
    }
  }
  R2[((size_t)enc * IMW + row) * IMW + x] = ((ull)hhi << 32) | hlo;
}

// ---------------------------------------------------------------------------
// k2: encoder convs. Tile 64x4 output pixels, 1 px/thread. Reads per-column
// histories; fast path: if no spike in the tile's 8x68 halo, output is 0.
// Slow path (correct for arbitrary inputs): ballot-transpose histories into
// per-t row bitmaps, then table-based conv1 + register conv2.
// ---------------------------------------------------------------------------
__global__ __launch_bounds__(256) void k2_enc(
    const ull* __restrict__ R2, const float* __restrict__ on_w1,
    const float* __restrict__ on_w2, const float* __restrict__ off_w1,
    const float* __restrict__ off_w2, float* __restrict__ means) {
  __shared__ ull hist[8][68];     // [local row r0-2..r0+5][col wcb*64-2..+65]
  __shared__ ull spk[64][8][2];   // [t][local row][A,B]
  __shared__ float4 t1v[512];     // relu(conv1) per 9-bit pattern
  int tid = threadIdx.x;
  int enc = blockIdx.z;
  int wcb = blockIdx.x;           // 64-column word index 0..7
  int r0 = blockIdx.y * 4;
  ull any = 0;
#pragma unroll
  for (int rep = 0; rep < 3; ++rep) {
    int idx = tid + 256 * rep;
    if (idx < 544) {
      int row = idx / 68, col = idx % 68;
      int gy = r0 - 2 + row, gx = wcb * 64 - 2 + col;
      ull h = 0;
      if (gy >= 0 && gy < IMW && gx >= 0 && gx < IMW)
        h = R2[((size_t)enc * IMW + gy) * IMW + gx];
      hist[row][col] = h;
      any |= h;
    }
  }
  int lane = tid & 63, wv = tid >> 6;
  int c = wcb * 64 + lane;
  int r = r0 + wv;
  float* outp = means + (size_t)enc * HW + r * IMW + c;
  int nz = __syncthreads_or(any != 0ull);
  if (!nz) { *outp = 0.0f; return; }

  // ---- slow path (not executed for all-zero spikes, but fully correct) ----
  // transpose hist -> spk: wave wv handles rows 2wv, 2wv+1
#pragma unroll 1
  for (int r2 = 0; r2 < 2; ++r2) {
    int row = wv * 2 + r2;
    ull hA = hist[row][lane];       // bit i of word A = col C-2+i
    ull hB = hist[row][lane + 4];   // bit i of word B = col C+2+i
    for (int t = 0; t < 64; ++t) {
      ull wA = __ballot((unsigned)((hA >> t) & 1ull));
      ull wB = __ballot((unsigned)((hB >> t) & 1ull));
      if (lane == t) { spk[t][row][0] = wA; spk[t][row][1] = wB; }
    }
  }
  const float* w1 = enc ? off_w1 : on_w1;
  const float* w2 = enc ? off_w2 : on_w2;
#pragma unroll
  for (int i = 0; i < 2; ++i) {
    int e = tid + 256 * i;
    float a0 = 0.f, a1 = 0.f, a2 = 0.f, a3 = 0.f;
#pragma unroll
    for (int k = 0; k < 9; ++k) {
      if (e & (1 << k)) {
        a0 += w1[k]; a1 += w1[9 + k]; a2 += w1[18 + k]; a3 += w1[27 + k];
      }
    }
    t1v[e] = make_float4(fmaxf(a0, 0.f), fmaxf(a1, 0.f),
                         fmaxf(a2, 0.f), fmaxf(a3, 0.f));
  }
  __syncthreads();
  float w2g[36];
#pragma unroll
  for (int i = 0; i < 36; ++i) w2g[i] = w2[i];
  float fm[9];   // conv2 zero-padding masks
#pragma unroll
  for (int qi = 0; qi < 3; ++qi)
#pragma unroll
    for (int dx = 0; dx < 3; ++dx) {
      int q = r - 1 + qi, xp = c - 1 + dx;
      fm[qi * 3 + dx] =
          (q >= 0 && q < IMW && xp >= 0 && xp < IMW) ? 1.0f : 0.0f;
    }
  int selB = (lane >= 60) ? 1 : 0;
  int shamt = selB ? lane - 4 : lane;
  float acc = 0.0f;
  for (int t = 0; t < 64; ++t) {
    unsigned r5[5];
#pragma unroll
    for (int k = 0; k < 5; ++k)
      r5[k] = (unsigned)((spk[t][wv + k][selB] >> shamt) & 31ull);
    float sum = 0.0f;
#pragma unroll
    for (int qi = 0; qi < 3; ++qi) {
#pragma unroll
      for (int dx = 0; dx < 3; ++dx) {
        unsigned pat = ((r5[qi] >> dx) & 7u) |
                       (((r5[qi + 1] >> dx) & 7u) << 3) |
                       (((r5[qi + 2] >> dx) & 7u) << 6);
        float4 sv = t1v[pat];
        int j = qi * 3 + dx;
        float d = w2g[j] * sv.x + w2g[9 + j] * sv.y + w2g[18 + j] * sv.z +
                  w2g[27 + j] * sv.w;
        sum = fmaf(fm[j], d, sum);
      }
    }
    acc += fmaxf(sum, 0.0f);
  }
  *outp = acc * (1.0f / 64.0f);
}

// ---------------------------------------------------------------------------
// k3: clip convs, fused. Out tile 8 rows x 64 cols per block (512 blocks).
// Phase1 (VALU fp32): stage = relu(conv1+b1) for tile+halo (10x66 positions),
//   zeroed outside the image (= conv2 zero padding), stored as f16 [pos][16ch].
// Phase2 (MFMA f16): conv2 as GEMM M=512 px, N=32 oc, K=144 (tap-major,
//   padded to 160). A-frag = ONE ds_read_b128 (8 lanes/bank-group, no
//   conflicts). B-frags held in VGPRs. D: oc=lane&15, px=(l>>4)*4+reg.
// Output stored non-temporally (write-once, never re-read in-pipeline).
// ---------------------------------------------------------------------------
__global__ __launch_bounds__(256) void k3_clip(
    const float* __restrict__ means, const float* __restrict__ rgb,
    const float* __restrict__ w1r, const float* __restrict__ b1,
    const _Float16* __restrict__ w2h, const float* __restrict__ b2,
    float* __restrict__ out) {
  __shared__ __align__(16) float xs[5][12][68];        // input tile + halo
  __shared__ __align__(16) _Float16 stage[660 * 16];   // [pos][ic] f16
  int tid = threadIdx.x;
  int c0 = blockIdx.x * 64;
  int r0 = blockIdx.y * 8;
  // ---- load x tile (On mean, Off mean, rgb x3), zero-padded: 4080 elems
#pragma unroll
  for (int k = 0; k < 16; ++k) {
    int idx = tid + 256 * k;
    if (idx < 4080) {
      int ch = idx / 816, rem = idx % 816;
      int row = rem / 68, col = rem % 68;
      int gy = r0 - 2 + row, gx = c0 - 2 + col;
      float val = 0.0f;
      if (gy >= 0 && gy < IMW && gx >= 0 && gx < IMW) {
        val = (ch < 2) ? means[(size_t)ch * HW + gy * IMW + gx]
                       : rgb[(size_t)(ch - 2) * HW + gy * IMW + gx];
      }
      xs[ch][row][col] = val;
    }
  }
  __syncthreads();
  // ---- phase 1: conv1 at 660 stage positions (10 x 66), <=3 per thread
#pragma unroll 1
  for (int rep = 0; rep < 3; ++rep) {
    int p = tid + (rep << 8);
    if (p < 660) {
      int sr = p / 66, sc = p % 66;
      float a[16];
#pragma unroll
      for (int oc = 0; oc < 16; ++oc) a[oc] = b1[oc];
#pragma unroll 1
      for (int ic = 0; ic < 5; ++ic) {
        const float* xp = &xs[ic][sr][sc];
#pragma unroll
        for (int dy = 0; dy < 3; ++dy) {
#pragma unroll
          for (int dx = 0; dx < 3; ++dx) {
            float x = xp[dy * 68 + dx];
            const float* wrow = w1r + (ic * 9 + dy * 3 + dx) * 16;
#pragma unroll
            for (int oc = 0; oc < 16; ++oc)
              a[oc] = fmaf(wrow[oc], x, a[oc]);
          }
        }
      }
      int q = r0 - 1 + sr, gxp = c0 - 1 + sc;
      float msk =
          (q >= 0 && q < IMW && gxp >= 0 && gxp < IMW) ? 1.0f : 0.0f;
      unsigned w[8];
#pragma unroll
      for (int j = 0; j < 8; ++j) {
        unsigned lo = (unsigned)__builtin_bit_cast(
            unsigned short, (_Float16)(msk * fmaxf(a[2 * j], 0.f)));
        unsigned hi = (unsigned)__builtin_bit_cast(
            unsigned short, (_Float16)(msk * fmaxf(a[2 * j + 1], 0.f)));
        w[j] = lo | (hi << 16);
      }
      uint4* dst = (uint4*)((char*)stage + p * 32);
      dst[0] = make_uint4(w[0], w[1], w[2], w[3]);
      dst[1] = make_uint4(w[4], w[5], w[6], w[7]);
    }
  }
  __syncthreads();
  // ---- phase 2: conv2 via MFMA. Wave og owns m-tiles og*8 .. og*8+7.
  int og = __builtin_amdgcn_readfirstlane(tid >> 6);
  int lane = tid & 63;
  int xl = lane & 15;
  int quad = lane >> 4;          // 0..3
  int ichalf = quad & 1;
  int q2 = quad >> 1;            // tap parity within chunk
  int myoff[5];
#pragma unroll
  for (int c = 0; c < 5; ++c) {
    int tap = 2 * c + q2;
    if (tap > 8) tap = 8;
    myoff[c] = ((tap / 3) * 66 + (tap % 3)) * 32;
  }
  h8 bf[5][2];
  const char* wb = (const char*)w2h;
#pragma unroll
  for (int c = 0; c < 5; ++c) {
#pragma unroll
    for (int nt = 0; nt < 2; ++nt) {
      int oc = nt * 16 + xl;
      f32x4 t = *(const f32x4*)(wb + oc * 320 + c * 64 + quad * 16);
      bf[c][nt] = __builtin_bit_cast(h8, t);
    }
  }
  float bias0 = b2[xl];
  float bias1 = b2[16 + xl];
#pragma unroll 1
  for (int mi = 0; mi < 8; ++mi) {
    int m = og * 8 + mi;
    int py = m >> 2;
    int x0 = (m & 3) << 4;
    int bb = ((py * 66 + x0 + xl) << 5) + (ichalf << 4);
    f32x4 acc0 = {0.f, 0.f, 0.f, 0.f};
    f32x4 acc1 = {0.f, 0.f, 0.f, 0.f};
#pragma unroll
    for (int c = 0; c < 5; ++c) {
      f32x4 ar = *(const f32x4*)((const char*)stage + bb + myoff[c]);
      h8 af = __builtin_bit_cast(h8, ar);
      acc0 = __builtin_amdgcn_mfma_f32_16x16x32_f16(af, bf[c][0], acc0, 0, 0, 0);
      acc1 = __builtin_amdgcn_mfma_f32_16x16x32_f16(af, bf[c][1], acc1, 0, 0, 0);
    }
    int px = c0 + x0 + ((lane >> 4) << 2);
    float* o0 = out + (size_t)xl * HW + (r0 + py) * IMW + px;
    float* o1 = o0 + (size_t)16 * HW;
    f32x4 r0v = {fmaxf(acc0[0] + bias0, 0.f), fmaxf(acc0[1] + bias0, 0.f),
                 fmaxf(acc0[2] + bias0, 0.f), fmaxf(acc0[3] + bias0, 0.f)};
    f32x4 r1v = {fmaxf(acc1[0] + bias1, 0.f), fmaxf(acc1[1] + bias1, 0.f),
                 fmaxf(acc1[2] + bias1, 0.f), fmaxf(acc1[3] + bias1, 0.f)};
    __builtin_nontemporal_store(r0v, (f32x4*)o0);
    __builtin_nontemporal_store(r1v, (f32x4*)o1);
  }
}

// ---------------------------------------------------------------------------
extern "C" void kernel_launch(void* const* d_in, const int* in_sizes, int n_in,
                              void* d_out, int out_size, void* d_ws,
                              size_t ws_size, hipStream_t stream) {
  const float* on_ev  = (const float*)d_in[0];
  const float* off_ev = (const float*)d_in[1];
  const float* rgb    = (const float*)d_in[2];
  const float* on_w1  = (const float*)d_in[3];
  const float* on_w2  = (const float*)d_in[4];
  const float* off_w1 = (const float*)d_in[5];
  const float* off_w2 = (const float*)d_in[6];
  const float* cw1    = (const float*)d_in[7];
  const float* cb1    = (const float*)d_in[8];
  const float* cw2    = (const float*)d_in[9];
  const float* cb2    = (const float*)d_in[10];
  float* out = (float*)d_out;
  char* ws = (char*)d_ws;
  ull* R2 = (ull*)ws;                         // 4 MB: per-column histories
  float* means = (float*)(ws + (4u << 20));   // 2 MB: On/Off mean maps
  float* w1r = (float*)(ws + (6u << 20));     // 2.8 KB (f32 conv1 weights)
  _Float16* w2h = (_Float16*)(ws + (6u << 20) + (16u << 10));  // 10 KB f16

  hipLaunchKernelGGL(k0_rearrange, dim3(20), dim3(256), 0, stream,
                     cw2, cw1, w2h, w1r);
  hipLaunchKernelGGL(k1_lif, dim3(2, 512, 2), dim3(256), 0, stream,
                     on_ev, off_ev, R2);
  hipLaunchKernelGGL(k2_enc, dim3(8, 128, 2), dim3(256), 0, stream,
                     R2, on_w1, on_w2, off_w1, off_w2, means);
  hipLaunchKernelGGL(k3_clip, dim3(8, 64), dim3(256), 0, stream,
                     means, rgb, w1r, cb1, w2h, cb2, out);
}